// Round 11
// baseline (37.611 us; speedup 1.0000x reference)
//
#include <hip/hip_runtime.h>

#define HH 128
#define TAB_N 4096
#define TAB_LO (-8.0f)
#define TAB_HI (8.0f)
#define NBLK 1024
#define ABLK 512   // kernel A: 512 blocks x 8 entries

// ws layout: [0,16KB) table

// ---------------------------------------------------------------------------
// Kernel A (register-resident W2): tabulate
//   y(u) = W3^T relu(W2^T relu(u*w1+b1) + b2) + b3
// on TAB_N uniform grid points, exact fp32. 512 blocks x 256 threads;
// 8 entries/block (2 blocks/CU -> 2 waves/SIMD, hides VALU+load latency).
// Thread (c = tid&31, ig = tid>>5) owns W2 rows 16ig..16ig+15, cols
// 4c..4c+3 in registers. Phase 1 all-register FMA; phase 2 one LDS round
// trip + 32-lane shfl reduce -> table entry.
// Block 0 zeroes d_out[64] for kernel B's hardware-fadd tail (plain stores;
// cross-kernel visibility via end-of-kernel release + stream order).
// ---------------------------------------------------------------------------
__global__ __launch_bounds__(256) void build_table_kernel(
    const float* __restrict__ W1, const float* __restrict__ b1,
    const float* __restrict__ W2, const float* __restrict__ b2,
    const float* __restrict__ W3, const float* __restrict__ b3,
    float* __restrict__ table, float* __restrict__ out)
{
    __shared__ float4 lds4[8 * 8 * 32];  // [entry][ig][c] = 32 KiB
    const int tid = threadIdx.x;
    const int c  = tid & 31;   // col-group: cols 4c..4c+3
    const int ig = tid >> 5;   // row-group: rows 16ig..16ig+15

    if (blockIdx.x == 0 && tid < 64) out[tid] = 0.0f;

    // --- register tiles ---
    float4 w2r[16];
    const float4* W2v = reinterpret_cast<const float4*>(W2);
#pragma unroll
    for (int r = 0; r < 16; ++r)
        w2r[r] = W2v[(16 * ig + r) * 32 + c];   // W2[row][4c..4c+3]

    float w1r[16], b1r[16];
#pragma unroll
    for (int r = 0; r < 16; ++r) {
        w1r[r] = W1[16 * ig + r];
        b1r[r] = b1[16 * ig + r];
    }

    const float step = (TAB_HI - TAB_LO) / (float)(TAB_N - 1);
    const int e0 = blockIdx.x * 8;

    // --- phase 1: all-register FMA for the block's 8 entries ---
    float4 facc[8];
#pragma unroll
    for (int e = 0; e < 8; ++e) {
        const float u = TAB_LO + step * (float)(e0 + e);
        float4 a = make_float4(0.f, 0.f, 0.f, 0.f);
#pragma unroll
        for (int r = 0; r < 16; ++r) {
            const float h1 = fmaxf(fmaf(u, w1r[r], b1r[r]), 0.0f);
            a.x = fmaf(h1, w2r[r].x, a.x);
            a.y = fmaf(h1, w2r[r].y, a.y);
            a.z = fmaf(h1, w2r[r].z, a.z);
            a.w = fmaf(h1, w2r[r].w, a.w);
        }
        facc[e] = a;
    }

    // --- phase 2: single LDS round trip + reduce ---
#pragma unroll
    for (int e = 0; e < 8; ++e)
        lds4[(e * 8 + ig) * 32 + c] = facc[e];
    __syncthreads();

    // 256 (entry, col-group) cells, exactly one per thread:
    //   e = tid>>5 (0..7), c2 = tid&31
    const int e  = tid >> 5;
    const int c2 = tid & 31;
    const float4* b2v = reinterpret_cast<const float4*>(b2);
    const float4* W3v = reinterpret_cast<const float4*>(W3);
    float4 s = make_float4(0.f, 0.f, 0.f, 0.f);
#pragma unroll
    for (int m = 0; m < 8; ++m) {
        const float4 v = lds4[(e * 8 + m) * 32 + c2];
        s.x += v.x; s.y += v.y; s.z += v.z; s.w += v.w;
    }
    const float4 bb = b2v[c2];
    const float4 ww = W3v[c2];
    float part = 0.0f;
    part += fmaxf(s.x + bb.x, 0.f) * ww.x;
    part += fmaxf(s.y + bb.y, 0.f) * ww.y;
    part += fmaxf(s.z + bb.z, 0.f) * ww.z;
    part += fmaxf(s.w + bb.w, 0.f) * ww.w;
    // entry e's 32 col-group partials live in one contiguous 32-lane group
    part += __shfl_xor(part, 1, 32);
    part += __shfl_xor(part, 2, 32);
    part += __shfl_xor(part, 4, 32);
    part += __shfl_xor(part, 8, 32);
    part += __shfl_xor(part, 16, 32);
    if (c2 == 0)
        table[e0 + e] = part + b3[0];
}

// ---------------------------------------------------------------------------
// Kernel B (R6 streaming body, proven): stream U as float4 (unroll x4 ->
// 4 independent global loads in flight per wave), nearest-neighbor y(u)
// from the 16 KiB LDS table (1 ds_read_b32 per element), block-reduce in
// LDS, then ONE wave-level hardware fp32 fadd atomic per block
// (unsafeAtomicAdd -> global_atomic_add_f32, no return, no CAS) straight
// into out[64] zeroed by kernel A. No counter, no fences, no finalize
// kernel. fp32 add-order jitter ~1e-6 << 2.3e-3 threshold.
// ---------------------------------------------------------------------------
__global__ __launch_bounds__(256) void mlp_mean_kernel(
    const float4* __restrict__ U4, const float* __restrict__ table,
    float* __restrict__ out, int nf4, float inv_n)
{
    __shared__ float tabs[TAB_N];   // 16 KiB
    __shared__ float4 red[256];     // 4 KiB
    const int tid = threadIdx.x;

    {
        const float4* tv = reinterpret_cast<const float4*>(table);
        float4* t4 = reinterpret_cast<float4*>(tabs);
#pragma unroll
        for (int j = 0; j < (TAB_N / 4) / 256; ++j)
            t4[tid + 256 * j] = tv[tid + 256 * j];
    }
    __syncthreads();

    const float step = (TAB_HI - TAB_LO) / (float)(TAB_N - 1);
    const float scale = 1.0f / step;
    const float bias = 0.5f - TAB_LO * scale;
    const float tmax = (float)(TAB_N - 1) + 0.49f;

    float4 acc = make_float4(0.f, 0.f, 0.f, 0.f);
    auto accum = [&](float4 v) {
        float t0 = fminf(fmaxf(fmaf(v.x, scale, bias), 0.f), tmax);
        float t1 = fminf(fmaxf(fmaf(v.y, scale, bias), 0.f), tmax);
        float t2 = fminf(fmaxf(fmaf(v.z, scale, bias), 0.f), tmax);
        float t3 = fminf(fmaxf(fmaf(v.w, scale, bias), 0.f), tmax);
        acc.x += tabs[(int)t0];
        acc.y += tabs[(int)t1];
        acc.z += tabs[(int)t2];
        acc.w += tabs[(int)t3];
    };

    const int stride = NBLK * 256;
    int f = blockIdx.x * 256 + tid;
    for (; f + 3 * stride < nf4; f += 4 * stride) {
        float4 v0 = U4[f];
        float4 v1 = U4[f + stride];
        float4 v2 = U4[f + 2 * stride];
        float4 v3 = U4[f + 3 * stride];
        accum(v0); accum(v1); accum(v2); accum(v3);
    }
    for (; f < nf4; f += stride)
        accum(U4[f]);

    red[tid] = acc;
    __syncthreads();

    if (tid < 64) {
        const int g = tid >> 2;   // float4-group covering output e = tid
        const int j = tid & 3;
        float s = 0.0f;
#pragma unroll
        for (int m = 0; m < 16; ++m) {
            const float* rp = reinterpret_cast<const float*>(&red[g + 16 * m]);
            s += rp[j];
        }
        // native fire-and-forget fp32 fadd (global_atomic_add_f32)
        unsafeAtomicAdd(out + tid, s * inv_n);
    }
}

extern "C" void kernel_launch(void* const* d_in, const int* in_sizes, int n_in,
                              void* d_out, int out_size, void* d_ws, size_t ws_size,
                              hipStream_t stream) {
    const float* U  = (const float*)d_in[0];
    const float* W1 = (const float*)d_in[1];
    const float* b1 = (const float*)d_in[2];
    const float* W2 = (const float*)d_in[3];
    const float* b2 = (const float*)d_in[4];
    const float* W3 = (const float*)d_in[5];
    const float* b3 = (const float*)d_in[6];
    float* out = (float*)d_out;

    float* table = (float*)d_ws;   // TAB_N floats = 16 KiB

    const int total = in_sizes[0];     // N * 64
    const int n_rows = total / 64;     // N
    const int nf4 = total / 4;

    build_table_kernel<<<ABLK, 256, 0, stream>>>(
        W1, b1, W2, b2, W3, b3, table, out);

    mlp_mean_kernel<<<NBLK, 256, 0, stream>>>(
        (const float4*)U, table, out, nf4, 1.0f / (float)n_rows);
}

// Round 12
// 18.590 us; speedup vs baseline: 2.0231x; 2.0231x over previous
//
#include <hip/hip_runtime.h>

#define HH 128
#define TAB_N 4096
#define TAB_LO (-8.0f)
#define TAB_HI (8.0f)
#define NBLK 1024
#define ABLK 512   // kernel A: 512 blocks x 8 entries

typedef float f32x4 __attribute__((ext_vector_type(4)));

// ws layout: [0,16KB) table | [16KB,+256KB) partial[NBLK][64] | [+4KB) flags[NBLK]

// coherent-point pipelined load (bypasses L1/XCD-L2; ordinary vmcnt load)
#define CLOAD4(dst, ptr)                                        \
    asm volatile("global_load_dwordx4 %0, %1, off sc0 sc1"      \
                 : "=v"(dst) : "v"(ptr))
// coherent-point fire-and-forget store
#define CSTORE1(ptr, val)                                       \
    asm volatile("global_store_dword %0, %1, off sc0 sc1"       \
                 :: "v"(ptr), "v"(val) : "memory")

// ---------------------------------------------------------------------------
// Kernel A (register-resident W2): tabulate
//   y(u) = W3^T relu(W2^T relu(u*w1+b1) + b2) + b3
// on TAB_N grid points, exact fp32. 512 blocks x 256 threads, 8 entries per
// block. Thread (c = tid&31, ig = tid>>5) owns W2 rows 16ig..16ig+15, cols
// 4c..4c+3 in registers. Phase 1 all-register FMA; phase 2 one LDS round
// trip + 32-lane shfl reduce. Block 0 resets the NBLK completion flags
// (plain stores; device-visible to B via A's end-of-kernel release).
// ---------------------------------------------------------------------------
__global__ __launch_bounds__(256) void build_table_kernel(
    const float* __restrict__ W1, const float* __restrict__ b1,
    const float* __restrict__ W2, const float* __restrict__ b2,
    const float* __restrict__ W3, const float* __restrict__ b3,
    float* __restrict__ table, float* __restrict__ flags)
{
    __shared__ float4 lds4[8 * 8 * 32];  // 32 KiB
    const int tid = threadIdx.x;
    const int c  = tid & 31;
    const int ig = tid >> 5;

    if (blockIdx.x == 0) {
        f32x4 z = {0.f, 0.f, 0.f, 0.f};
        reinterpret_cast<f32x4*>(flags)[tid] = z;   // 256 x 16B = 1024 flags
    }

    float4 w2r[16];
    const float4* W2v = reinterpret_cast<const float4*>(W2);
#pragma unroll
    for (int r = 0; r < 16; ++r)
        w2r[r] = W2v[(16 * ig + r) * 32 + c];

    float w1r[16], b1r[16];
#pragma unroll
    for (int r = 0; r < 16; ++r) {
        w1r[r] = W1[16 * ig + r];
        b1r[r] = b1[16 * ig + r];
    }

    const float step = (TAB_HI - TAB_LO) / (float)(TAB_N - 1);
    const int e0 = blockIdx.x * 8;

    float4 facc[8];
#pragma unroll
    for (int e = 0; e < 8; ++e) {
        const float u = TAB_LO + step * (float)(e0 + e);
        float4 a = make_float4(0.f, 0.f, 0.f, 0.f);
#pragma unroll
        for (int r = 0; r < 16; ++r) {
            const float h1 = fmaxf(fmaf(u, w1r[r], b1r[r]), 0.0f);
            a.x = fmaf(h1, w2r[r].x, a.x);
            a.y = fmaf(h1, w2r[r].y, a.y);
            a.z = fmaf(h1, w2r[r].z, a.z);
            a.w = fmaf(h1, w2r[r].w, a.w);
        }
        facc[e] = a;
    }

#pragma unroll
    for (int e = 0; e < 8; ++e)
        lds4[(e * 8 + ig) * 32 + c] = facc[e];
    __syncthreads();

    const int e  = tid >> 5;   // 0..7
    const int c2 = tid & 31;
    const float4* b2v = reinterpret_cast<const float4*>(b2);
    const float4* W3v = reinterpret_cast<const float4*>(W3);
    float4 s = make_float4(0.f, 0.f, 0.f, 0.f);
#pragma unroll
    for (int m = 0; m < 8; ++m) {
        const float4 v = lds4[(e * 8 + m) * 32 + c2];
        s.x += v.x; s.y += v.y; s.z += v.z; s.w += v.w;
    }
    const float4 bb = b2v[c2];
    const float4 ww = W3v[c2];
    float part = 0.0f;
    part += fmaxf(s.x + bb.x, 0.f) * ww.x;
    part += fmaxf(s.y + bb.y, 0.f) * ww.y;
    part += fmaxf(s.z + bb.z, 0.f) * ww.z;
    part += fmaxf(s.w + bb.w, 0.f) * ww.w;
    part += __shfl_xor(part, 1, 32);
    part += __shfl_xor(part, 2, 32);
    part += __shfl_xor(part, 4, 32);
    part += __shfl_xor(part, 8, 32);
    part += __shfl_xor(part, 16, 32);
    if (c2 == 0)
        table[e0 + e] = part + b3[0];
}

// ---------------------------------------------------------------------------
// Kernel B: R6's proven streaming body (1024 blocks, x4 unroll, NN lookup
// from 16 KiB LDS table), then a fused finalize with ZERO atomics:
//  - every block: wave 0 publishes 64 partials via sc0sc1 dword stores,
//    s_waitcnt vmcnt(0), then one sc0sc1 flag store (pure fire-and-forget;
//    no RMW chain -> none of the R7-R11 serialization).
//  - blocks 0..15: poll all NBLK flags with pipelined sc0sc1 f32x4 loads
//    (+ s_sleep between sweeps), then block q reads partial[.][q] slice
//    (4 pipelined sc0sc1 loads/thread), LDS tree-reduce in FIXED order,
//    write out[4q..4q+3]. Deterministic. All blocks co-resident (20 KB LDS,
//    4 blk/CU) -> no deadlock.
// ---------------------------------------------------------------------------
__global__ __launch_bounds__(256) void mlp_mean_kernel(
    const float4* __restrict__ U4, const float* __restrict__ table,
    float* __restrict__ partial, float* __restrict__ flags,
    float* __restrict__ out, int nf4, float inv_n)
{
    __shared__ float tabs[TAB_N];   // 16 KiB
    __shared__ float4 red[256];     // 4 KiB
    const int tid = threadIdx.x;

    {
        const float4* tv = reinterpret_cast<const float4*>(table);
        float4* t4 = reinterpret_cast<float4*>(tabs);
#pragma unroll
        for (int j = 0; j < (TAB_N / 4) / 256; ++j)
            t4[tid + 256 * j] = tv[tid + 256 * j];
    }
    __syncthreads();

    const float step = (TAB_HI - TAB_LO) / (float)(TAB_N - 1);
    const float scale = 1.0f / step;
    const float bias = 0.5f - TAB_LO * scale;
    const float tmax = (float)(TAB_N - 1) + 0.49f;

    float4 acc = make_float4(0.f, 0.f, 0.f, 0.f);
    auto accum = [&](float4 v) {
        float t0 = fminf(fmaxf(fmaf(v.x, scale, bias), 0.f), tmax);
        float t1 = fminf(fmaxf(fmaf(v.y, scale, bias), 0.f), tmax);
        float t2 = fminf(fmaxf(fmaf(v.z, scale, bias), 0.f), tmax);
        float t3 = fminf(fmaxf(fmaf(v.w, scale, bias), 0.f), tmax);
        acc.x += tabs[(int)t0];
        acc.y += tabs[(int)t1];
        acc.z += tabs[(int)t2];
        acc.w += tabs[(int)t3];
    };

    const int stride = NBLK * 256;
    int f = blockIdx.x * 256 + tid;
    for (; f + 3 * stride < nf4; f += 4 * stride) {
        float4 v0 = U4[f];
        float4 v1 = U4[f + stride];
        float4 v2 = U4[f + 2 * stride];
        float4 v3 = U4[f + 3 * stride];
        accum(v0); accum(v1); accum(v2); accum(v3);
    }
    for (; f < nf4; f += stride)
        accum(U4[f]);

    red[tid] = acc;
    __syncthreads();

    // --- publish: wave 0 only (64 lanes = one wave; vmcnt covers all) ---
    if (tid < 64) {
        const int g = tid >> 2;
        const int j = tid & 3;
        float s = 0.0f;
#pragma unroll
        for (int m = 0; m < 16; ++m) {
            const float* rp = reinterpret_cast<const float*>(&red[g + 16 * m]);
            s += rp[j];
        }
        float* pp = partial + blockIdx.x * 64 + tid;
        CSTORE1(pp, s);
        asm volatile("s_waitcnt vmcnt(0)" ::: "memory");
        if (tid == 0) {
            float one = 1.0f;
            float* fp = flags + blockIdx.x;
            CSTORE1(fp, one);
        }
    }

    if (blockIdx.x >= 16) return;

    // --- finalizer blocks 0..15: q = blockIdx.x ---
    const int q = blockIdx.x;

    // poll all NBLK flags: 256 threads x 1 f32x4 = 1024 flags per sweep
    const f32x4* fl4 = reinterpret_cast<const f32x4*>(flags);
    for (;;) {
        f32x4 v;
        CLOAD4(v, fl4 + tid);
        asm volatile("s_waitcnt vmcnt(0)" : "+v"(v));
        int ok = (v.x == 1.0f) && (v.y == 1.0f) && (v.z == 1.0f) && (v.w == 1.0f);
        if (__syncthreads_count(ok) == 256) break;
        __builtin_amdgcn_s_sleep(2);
    }

    // read partial[.][q]: rows tid, tid+256, tid+512, tid+768 (pipelined)
    const f32x4* p4 = reinterpret_cast<const f32x4*>(partial);  // [NBLK][16]
    f32x4 v0, v1, v2, v3;
    CLOAD4(v0, p4 + ((size_t)(tid        ) * 16 + q));
    CLOAD4(v1, p4 + ((size_t)(tid +  256 ) * 16 + q));
    CLOAD4(v2, p4 + ((size_t)(tid +  512 ) * 16 + q));
    CLOAD4(v3, p4 + ((size_t)(tid +  768 ) * 16 + q));
    asm volatile("s_waitcnt vmcnt(0)"
                 : "+v"(v0), "+v"(v1), "+v"(v2), "+v"(v3));
    f32x4 s = ((v0 + v1) + v2) + v3;

    // fixed-order LDS tree reduce 256 -> 1 (reuse red; poll-sync ordered it)
    red[tid] = make_float4(s.x, s.y, s.z, s.w);
    __syncthreads();
#pragma unroll
    for (int off = 128; off > 0; off >>= 1) {
        if (tid < off) {
            float4 a = red[tid], b = red[tid + off];
            a.x += b.x; a.y += b.y; a.z += b.z; a.w += b.w;
            red[tid] = a;
        }
        __syncthreads();
    }
    if (tid == 0) {
        float4 t = red[0];
        out[q * 4 + 0] = t.x * inv_n;
        out[q * 4 + 1] = t.y * inv_n;
        out[q * 4 + 2] = t.z * inv_n;
        out[q * 4 + 3] = t.w * inv_n;
    }
}

extern "C" void kernel_launch(void* const* d_in, const int* in_sizes, int n_in,
                              void* d_out, int out_size, void* d_ws, size_t ws_size,
                              hipStream_t stream) {
    const float* U  = (const float*)d_in[0];
    const float* W1 = (const float*)d_in[1];
    const float* b1 = (const float*)d_in[2];
    const float* W2 = (const float*)d_in[3];
    const float* b2 = (const float*)d_in[4];
    const float* W3 = (const float*)d_in[5];
    const float* b3 = (const float*)d_in[6];
    float* out = (float*)d_out;

    float* table   = (float*)d_ws;                        // 16 KiB
    float* partial = (float*)d_ws + TAB_N;                // NBLK*64 floats
    float* flags   = (float*)d_ws + TAB_N + NBLK * 64;    // NBLK floats

    const int total = in_sizes[0];     // N * 64
    const int n_rows = total / 64;     // N
    const int nf4 = total / 4;

    build_table_kernel<<<ABLK, 256, 0, stream>>>(
        W1, b1, W2, b2, W3, b3, table, flags);

    mlp_mean_kernel<<<NBLK, 256, 0, stream>>>(
        (const float4*)U, table, partial, flags, out, nf4,
        1.0f / (float)n_rows);
}